// Round 14
// baseline (287.797 us; speedup 1.0000x reference)
//
#include <hip/hip_runtime.h>
#include <stdint.h>
#include <type_traits>

// Problem constants
#define BB  4
#define SS  2048
#define DD  1024
#define HH  16
#define HDD 64

typedef __attribute__((ext_vector_type(8))) short s16x8;   // 8 bf16 (4 VGPRs)
typedef __attribute__((ext_vector_type(4))) float f32x4;   // MFMA C/D

__device__ inline short f2bf(float f) {
    union { float f; unsigned int u; } v; v.f = f;
    unsigned int r = (v.u + 0x7fffu + ((v.u >> 16) & 1u)) >> 16; // RNE
    return (short)r;
}

__device__ inline unsigned int pk2(float a, float b) {
    return (unsigned int)(unsigned short)f2bf(a) |
           ((unsigned int)(unsigned short)f2bf(b) << 16);
}

#define GLL(gp, lp) __builtin_amdgcn_global_load_lds( \
    (const __attribute__((address_space(1))) void*)(gp), \
    (__attribute__((address_space(3))) void*)(lp), 16, 0, 0)

// Raw barrier: orders this wave's LDS ops (lgkmcnt) then syncs. Does NOT
// drain vmcnt -> global_load_lds prefetch stays in flight across it.
__device__ inline void lds_barrier() {
    asm volatile("s_waitcnt lgkmcnt(0)" ::: "memory");
    __builtin_amdgcn_sched_barrier(0);
    __builtin_amdgcn_s_barrier();
    __builtin_amdgcn_sched_barrier(0);
}

// ---------------- fused fp32 -> bf16 cast of all three inputs ----------------
__global__ void cvt_all(const float* __restrict__ x, const float* __restrict__ qw,
                        const float* __restrict__ ow, short* __restrict__ dst) {
    const int X_N  = BB * SS * DD;          // 8388608
    const int QW_N = 3 * DD * DD;           // 3145728
    int i = (blockIdx.x * 256 + threadIdx.x) * 8;
    const float* s;
    if (i < X_N)            s = x + i;
    else if (i < X_N + QW_N) s = qw + (i - X_N);
    else                     s = ow + (i - X_N - QW_N);
    const float4* sp = (const float4*)s;
    float4 a = sp[0], b = sp[1];
    s16x8 o;
    o[0]=f2bf(a.x); o[1]=f2bf(a.y); o[2]=f2bf(a.z); o[3]=f2bf(a.w);
    o[4]=f2bf(b.x); o[5]=f2bf(b.y); o[6]=f2bf(b.z); o[7]=f2bf(b.w);
    *(s16x8*)(dst + i) = o;
}

// ---------------- GEMM C = A @ B^T + bias (BM=BN=128, BK=32, TRIPLE buffer) --------
// (unchanged from round 13 - best measured of six structural variants)
template<int EPI>
__global__ __launch_bounds__(256, 3)
void gemm128tb(const short* __restrict__ A, const short* __restrict__ Bw,
               const float* __restrict__ bias, float* __restrict__ Cf,
               short* __restrict__ Qo, short* __restrict__ Ko, short* __restrict__ Vo,
               int M, int N, int K, int nbx)
{
    __shared__ short lsA[3][128 * 32];
    __shared__ short lsB[3][128 * 32];

    const int tid  = threadIdx.x;
    const int w    = tid >> 6, lane = tid & 63;
    const int quad = lane >> 4, l15 = lane & 15;
    const int wm = w >> 1, wn = w & 1;
    const int cpx = gridDim.x >> 3;             // T1 XCD swizzle (grid % 8 == 0)
    const int swz = (blockIdx.x & 7) * cpx + (blockIdx.x >> 3);
    const int m0 = (swz / nbx) * 128, n0 = (swz % nbx) * 128;
    const int grow = lane >> 2;                 // row-within-chunk this lane covers
    const int gcol = ((lane & 3) ^ (grow & 3)) * 8;  // inverse-swizzled src granule
    const int rsw = (l15 & 3);                  // reader XOR term (row&3 == l15&3)

    f32x4 acc[4][4] = {};

    auto issue = [&](int kt, int buf) {
#pragma unroll
        for (int jj = 0; jj < 2; ++jj) {        // A: 128 rows = 8 chunks, 2/wave
            int c = w * 2 + jj;
            GLL(A + (size_t)(m0 + c * 16 + grow) * K + kt * 32 + gcol,
                &lsA[buf][c * 512]);
        }
#pragma unroll
        for (int jj = 0; jj < 2; ++jj) {        // B: 128 rows = 8 chunks, 2/wave
            int c = w * 2 + jj;
            GLL(Bw + (size_t)(n0 + c * 16 + grow) * K + kt * 32 + gcol,
                &lsB[buf][c * 512]);
        }
    };

    const int NT = K >> 5;                      // BK=32 K-tiles (32 here)
    issue(0, 0);
    issue(1, 1);
    int buf = 0;                                // t % 3
    for (int t = 0; t < NT; ++t) {
        lds_barrier();                          // A: buf[(t+2)%3] readers (t-1) done
        const int nb2 = (buf + 2 >= 3) ? buf - 1 : buf + 2;   // (t+2)%3
        if (t + 2 < NT) {
            issue(t + 2, nb2);
            asm volatile("s_waitcnt vmcnt(8)" ::: "memory");   // stage(t) landed; ~free
        } else if (t + 1 < NT) {
            asm volatile("s_waitcnt vmcnt(4)" ::: "memory");
        } else {
            asm volatile("s_waitcnt vmcnt(0)" ::: "memory");
        }
        __builtin_amdgcn_sched_barrier(0);
        __builtin_amdgcn_s_barrier();           // B: tile t fully staged (all waves)
        __builtin_amdgcn_sched_barrier(0);

        s16x8 af[4], bfr[4];
#pragma unroll
        for (int mf = 0; mf < 4; ++mf)
            af[mf] = *(const s16x8*)&lsA[buf][(wm * 64 + mf * 16 + l15) * 32 +
                                             ((quad ^ rsw) * 8)];
#pragma unroll
        for (int nf = 0; nf < 4; ++nf)
            bfr[nf] = *(const s16x8*)&lsB[buf][(wn * 64 + nf * 16 + l15) * 32 +
                                              ((quad ^ rsw) * 8)];

        __builtin_amdgcn_s_setprio(1);
#pragma unroll
        for (int mf = 0; mf < 4; ++mf)
#pragma unroll
            for (int nf = 0; nf < 4; ++nf)
                acc[mf][nf] = __builtin_amdgcn_mfma_f32_16x16x32_bf16(
                                  af[mf], bfr[nf], acc[mf][nf], 0, 0, 0);
        __builtin_amdgcn_s_setprio(0);

        buf = (buf + 1 >= 3) ? 0 : buf + 1;
    }

    if (EPI == 0) {
#pragma unroll
        for (int mf = 0; mf < 4; ++mf) {
            int row = m0 + wm * 64 + mf * 16 + quad * 4;
#pragma unroll
            for (int nf = 0; nf < 4; ++nf) {
                int col = n0 + wn * 64 + nf * 16 + l15;
                float bv = bias[col];
#pragma unroll
                for (int r = 0; r < 4; ++r)
                    Cf[(size_t)(row + r) * N + col] = acc[mf][nf][r] + bv;
            }
        }
    } else {
#pragma unroll
        for (int mf = 0; mf < 4; ++mf) {
            int row = m0 + wm * 64 + mf * 16 + quad * 4;
#pragma unroll
            for (int nf = 0; nf < 4; ++nf) {
                int col = n0 + wn * 64 + nf * 16 + l15;
                float bv = bias[col];
                int sel = col >> 10, h = (col >> 6) & 15, hd = col & 63;
#pragma unroll
                for (int r = 0; r < 4; ++r) {
                    int rr = row + r;
                    int b = rr >> 11, s = rr & 2047;
                    short val = f2bf(acc[mf][nf][r] + bv);
                    if (sel == 0)      Qo[(((size_t)b * HH + h) * SS + s) * HDD + hd] = val;
                    else if (sel == 1) Ko[(((size_t)b * HH + h) * SS + s) * HDD + hd] = val;
                    else               Vo[(((size_t)b * HH + h) * HDD + hd) * SS + s] = val;
                }
            }
        }
    }
}

// ---------------- causal flash attention (swapped QK^T, KVBLK=128) -----------------
// r13 structure with KVBLK 64->128: per-key fixed costs (2 barriers + vmcnt + mask)
// halved. Fits 2 blocks/CU at exactly 80 KB by (a) mask int4-loads direct from
// global (L1-hot; issued BEFORE the prefetch GLLs so the counted vmcnt's FIFO
// drains them with the current tile), (b) PV in two k-halves reusing the SAME
// 16KB wave-private P buffer (same-wave DS ordering makes the WAR safe).
// V rows now 256B (16 granules; XOR low-3 with row&7, both sides - rule #21).
// K path and P layout identical to the r10-verified patterns.
__global__ __launch_bounds__(256, 2)
void attn_kernel(const short* __restrict__ Q, const short* __restrict__ Kb,
                 const short* __restrict__ Vb, const int* __restrict__ mask,
                 short* __restrict__ O)
{
    __shared__ short lsK[2][128 * 64];     // [buf][key][hd] 128B rows, src-swizzled
    __shared__ short lsV[2][64 * 128];     // [buf][hd][key] 256B rows, src-swizzled
    __shared__ short lsP[4][32 * 64];      // per-wave P half (reused for both halves)

    const int tid  = threadIdx.x;
    const int w    = tid >> 6, lane = tid & 63;
    const int quad = lane >> 4, l15 = lane & 15;
    const int L  = blockIdx.x + 8 * blockIdx.y;      // [0,512)
    const int bx = L >> 6;                           // [0,8)
    const int bh = (L & 7) * 8 + ((L >> 3) & 7);     // [0,64), same-XCD groups
    const int b = bh >> 4;
    const size_t baseQK = (size_t)bh * SS * HDD;
    const size_t baseV  = (size_t)bh * HDD * SS;
    const float SC = 0.18033688f;          // (1/8) * log2(e)
    const int grow = lane >> 3;            // K-GLL: row-within-8 covered by this lane
    const int gcol = ((lane & 7) ^ grow) * 8;  // K-GLL: inverse-swizzled source col
    const int l7 = l15 & 7;
    const int vrow_in = lane >> 4;         // V-GLL: row-within-4 covered by this lane

    // issue tile (kv0) K/V global->LDS DMA into buffer buf: 8 GLL per wave
    auto issue = [&](int kv0, int buf) {
#pragma unroll
        for (int jj = 0; jj < 4; ++jj) {   // K: 128 rows -> 16 chunks (8r x 128B)
            int c = w * 4 + jj;
            GLL(Kb + baseQK + (size_t)(kv0 + c * 8 + grow) * HDD + gcol,
                &lsK[buf][c * 512]);
        }
#pragma unroll
        for (int jj = 0; jj < 4; ++jj) {   // V: 64 rows -> 16 chunks (4r x 256B)
            int c = w * 4 + jj;
            int vrow = c * 4 + vrow_in;
            int vg = (lane & 15) ^ (vrow & 7);
            GLL(Vb + baseV + (size_t)vrow * SS + kv0 + vg * 8,
                &lsV[buf][c * 512]);
        }
    };

    for (int t = 0; t < 2; ++t) {
        const int qb = t ? bx : (15 - bx);  // heavy q-tile first
        const int q0 = qb * 128;
        const int qw0 = q0 + w * 32;        // this wave's first q-row

        s16x8 aq[2][2];
#pragma unroll
        for (int s = 0; s < 2; ++s)
#pragma unroll
            for (int ks = 0; ks < 2; ++ks)
                aq[s][ks] = *(const s16x8*)(Q + baseQK +
                    (size_t)(qw0 + s * 16 + l15) * HDD + ks * 32 + quad * 8);

        float m_r[2], l_r[2];
        f32x4 o_acc[2][4] = {};
#pragma unroll
        for (int s = 0; s < 2; ++s) { m_r[s] = -1e30f; l_r[s] = 0.f; }

        const int ntiles = qb + 1;          // 128-key tiles; last is diagonal

        lds_barrier();                      // prev t's reads done
        issue(0, 0);

        auto tile = [&](auto CC, int kv0, int buf, int kvn) {
            constexpr bool CAUS = decltype(CC)::value;

            lds_barrier();                  // A: all waves done reading buf^1

            // mask additive from global (BEFORE prefetch GLLs: vmcnt FIFO order!)
            float madd[8][4];
#pragma unroll
            for (int nt = 0; nt < 8; ++nt) {
                int4 mi = *(const int4*)(mask + b * SS + kv0 + nt * 16 + quad * 4);
                madd[nt][0] = mi.x ? 0.f : -1e30f;
                madd[nt][1] = mi.y ? 0.f : -1e30f;
                madd[nt][2] = mi.z ? 0.f : -1e30f;
                madd[nt][3] = mi.w ? 0.f : -1e30f;
            }
            __builtin_amdgcn_sched_barrier(0);
            if (kvn >= 0) issue(kvn, buf ^ 1);

            // counted wait: drains tile-t GLLs + mask loads; kvn's 8 stay in flight
            if (kvn >= 0) asm volatile("s_waitcnt vmcnt(8)" ::: "memory");
            else          asm volatile("s_waitcnt vmcnt(0)" ::: "memory");
            __builtin_amdgcn_sched_barrier(0);
            __builtin_amdgcn_s_barrier();   // B: all waves' GLLs for buf landed
            __builtin_amdgcn_sched_barrier(0);

            // S^T = K Q^T : D[key][q]; lane holds q=l15, key=kv0+nt*16+quad*4+r
            f32x4 sv[2][8];
#pragma unroll
            for (int s = 0; s < 2; ++s)
#pragma unroll
                for (int nt = 0; nt < 8; ++nt) sv[s][nt] = f32x4{};
#pragma unroll
            for (int ks = 0; ks < 2; ++ks)
#pragma unroll
                for (int nt = 0; nt < 8; ++nt) {
                    s16x8 kf = *(const s16x8*)&lsK[buf][(nt * 16 + l15) * 64 +
                                                       (((ks * 4 + quad) ^ l7) * 8)];
#pragma unroll
                    for (int s = 0; s < 2; ++s)
                        sv[s][nt] = __builtin_amdgcn_mfma_f32_16x16x32_bf16(
                                        kf, aq[s][ks], sv[s][nt], 0, 0, 0);
                }

            // scale + key-mask + causal (k lane-indexed, q = l15)
#pragma unroll
            for (int s = 0; s < 2; ++s) {
                const int qg = qw0 + s * 16 + l15;
#pragma unroll
                for (int nt = 0; nt < 8; ++nt) {
                    const int kg0 = kv0 + nt * 16 + quad * 4;
#pragma unroll
                    for (int r = 0; r < 4; ++r) {
                        float scv = sv[s][nt][r] * SC + madd[nt][r];
                        if (CAUS && kg0 + r > qg) scv = -1e30f;
                        sv[s][nt][r] = scv;
                    }
                }
            }

            // row max over keys: 32 in-lane + cross-quad (2 shfl)
            float rm[2];
#pragma unroll
            for (int s = 0; s < 2; ++s) {
                float v = -1e30f;
#pragma unroll
                for (int nt = 0; nt < 8; ++nt)
                    v = fmaxf(v, fmaxf(fmaxf(sv[s][nt][0], sv[s][nt][1]),
                                       fmaxf(sv[s][nt][2], sv[s][nt][3])));
                v = fmaxf(v, __shfl_xor(v, 16));
                v = fmaxf(v, __shfl_xor(v, 32));
                rm[s] = v;
            }
            // T13 defer-max
            float need = fmaxf(rm[0] - m_r[0], rm[1] - m_r[1]);
            if (!__all(need <= 8.0f)) {
#pragma unroll
                for (int s = 0; s < 2; ++s) {
                    float nm = fmaxf(m_r[s], rm[s]);
                    float al = __builtin_amdgcn_exp2f(m_r[s] - nm);
                    m_r[s] = nm;
                    l_r[s] *= al;
#pragma unroll
                    for (int r = 0; r < 4; ++r) {
                        float alq = __shfl(al, (quad << 2) + r + (lane & 48));
#pragma unroll
                        for (int ht = 0; ht < 4; ++ht)
                            o_acc[s][ht][r] *= alq;
                    }
                }
            }
            // P = exp2(S - m); per-lane partial l
#pragma unroll
            for (int s = 0; s < 2; ++s) {
                float rs = 0.f;
#pragma unroll
                for (int nt = 0; nt < 8; ++nt)
#pragma unroll
                    for (int r = 0; r < 4; ++r) {
                        float p = __builtin_amdgcn_exp2f(sv[s][nt][r] - m_r[s]);
                        sv[s][nt][r] = p;
                        rs += p;
                    }
                l_r[s] += rs;
            }

            // PV in two k-halves, reusing the same wave-private P buffer.
            short* lsPw = lsP[w];
#pragma unroll
            for (int half = 0; half < 2; ++half) {
                // P half -> lsPw (r10-verified layout, keys half*64..+64)
#pragma unroll
                for (int s = 0; s < 2; ++s)
#pragma unroll
                    for (int nt2 = 0; nt2 < 4; ++nt2) {
                        int nt = half * 4 + nt2;
                        uint2 pw;
                        pw.x = pk2(sv[s][nt][0], sv[s][nt][1]);
                        pw.y = pk2(sv[s][nt][2], sv[s][nt][3]);
                        int row = s * 16 + l15;
                        int g8 = (nt2 * 2 + (quad >> 1)) ^ l7;
                        *(uint2*)&lsPw[row * 64 + (g8 << 3) + ((quad & 1) << 2)] = pw;
                    }
                asm volatile("s_waitcnt lgkmcnt(0)" ::: "memory");
                __builtin_amdgcn_sched_barrier(0);

                s16x8 ap[2][2];
#pragma unroll
                for (int s = 0; s < 2; ++s)
#pragma unroll
                    for (int k2 = 0; k2 < 2; ++k2)
                        ap[s][k2] = *(const s16x8*)&lsPw[(s * 16 + l15) * 64 +
                                                         (((k2 * 4 + quad) ^ l7) << 3)];
#pragma unroll
                for (int ht = 0; ht < 4; ++ht)
#pragma unroll
                    for (int k2 = 0; k2 < 2; ++k2) {
                        s16x8 vf = *(const s16x8*)&lsV[buf][(ht * 16 + l15) * 128 +
                                        (((half * 8 + k2 * 4 + quad) ^ l7) * 8)];
#pragma unroll
                        for (int s = 0; s < 2; ++s)
                            o_acc[s][ht] = __builtin_amdgcn_mfma_f32_16x16x32_bf16(
                                               ap[s][k2], vf, o_acc[s][ht], 0, 0, 0);
                    }
            }
        };

        for (int kt = 0; kt < ntiles; ++kt) {
            const int kvn = (kt + 1 < ntiles) ? (kt + 1) * 128 : -1;
            if (kt == ntiles - 1) tile(std::true_type{},  kt * 128, kt & 1, kvn);
            else                  tile(std::false_type{}, kt * 128, kt & 1, kvn);
        }

        // epilogue: sum l across quads, redistribute to o_acc rows, write O
        const int hcol = (bh & 15) * HDD;
#pragma unroll
        for (int s = 0; s < 2; ++s) {
            float ls = l_r[s];
            ls += __shfl_xor(ls, 16);
            ls += __shfl_xor(ls, 32);      // full row-sum for q = l15
#pragma unroll
            for (int r = 0; r < 4; ++r) {
                float lq = __shfl(ls, (quad << 2) + r + (lane & 48));
                float inv = 1.0f / lq;
                int srow = qw0 + s * 16 + quad * 4 + r;
                size_t base = ((size_t)b * SS + srow) * DD + hcol;
#pragma unroll
                for (int ht = 0; ht < 4; ++ht)
                    O[base + ht * 16 + l15] = f2bf(o_acc[s][ht][r] * inv);
            }
        }
    }
}

// ---------------- launch ----------------
extern "C" void kernel_launch(void* const* d_in, const int* in_sizes, int n_in,
                              void* d_out, int out_size, void* d_ws, size_t ws_size,
                              hipStream_t stream) {
    const float* x     = (const float*)d_in[0];
    const int*   mask  = (const int*)d_in[1];
    const float* qkv_w = (const float*)d_in[2];
    const float* qkv_b = (const float*)d_in[3];
    const float* out_w = (const float*)d_in[4];
    const float* out_b = (const float*)d_in[5];
    float* out = (float*)d_out;

    const size_t M1 = (size_t)BB * SS;       // 8192
    short* ws  = (short*)d_ws;
    short* xb  = ws;
    short* qwb = xb  + M1 * DD;
    short* owb = qwb + (size_t)3 * DD * DD;
    short* Qb  = owb + (size_t)DD * DD;
    short* Kb  = Qb  + M1 * DD;
    short* Vb  = Kb  + M1 * DD;
    short* Ob  = Vb  + M1 * DD;

    // fused cast: (8192*1024 + 3*1024*1024 + 1024*1024) / 8 / 256 = 6144 blocks
    cvt_all<<<6144, 256, 0, stream>>>(x, qkv_w, out_w, ws);

    // qkv: M=8192, N=3072 -> 64 x 24 = 1536 blocks (3/CU by LDS)
    gemm128tb<1><<<1536, 256, 0, stream>>>(xb, qwb, qkv_b, nullptr,
                                           Qb, Kb, Vb, 8192, 3072, 1024, 24);
    attn_kernel<<<dim3(8, BB * HH), 256, 0, stream>>>(Qb, Kb, Vb, mask, Ob);
    // out: M=8192, N=1024 -> 64 x 8 = 512 blocks
    gemm128tb<0><<<512, 256, 0, stream>>>(Ob, owb, out_b, out,
                                          nullptr, nullptr, nullptr, 8192, 1024, 1024, 8);
}

// Round 15
// 282.766 us; speedup vs baseline: 1.0178x; 1.0178x over previous
//
#include <hip/hip_runtime.h>
#include <stdint.h>
#include <type_traits>

// Problem constants
#define BB  4
#define SS  2048
#define DD  1024
#define HH  16
#define HDD 64

typedef __attribute__((ext_vector_type(8))) short s16x8;   // 8 bf16 (4 VGPRs)
typedef __attribute__((ext_vector_type(4))) float f32x4;   // MFMA C/D

__device__ inline short f2bf(float f) {
    union { float f; unsigned int u; } v; v.f = f;
    unsigned int r = (v.u + 0x7fffu + ((v.u >> 16) & 1u)) >> 16; // RNE
    return (short)r;
}

__device__ inline float bf2f(short s) {
    union { unsigned int u; float f; } v;
    v.u = ((unsigned int)(unsigned short)s) << 16;
    return v.f;
}

__device__ inline unsigned int pk2(float a, float b) {
    return (unsigned int)(unsigned short)f2bf(a) |
           ((unsigned int)(unsigned short)f2bf(b) << 16);
}

#define GLL(gp, lp) __builtin_amdgcn_global_load_lds( \
    (const __attribute__((address_space(1))) void*)(gp), \
    (__attribute__((address_space(3))) void*)(lp), 16, 0, 0)

// Raw barrier: orders this wave's LDS ops (lgkmcnt) then syncs. Does NOT
// drain vmcnt -> global_load_lds prefetch stays in flight across it.
__device__ inline void lds_barrier() {
    asm volatile("s_waitcnt lgkmcnt(0)" ::: "memory");
    __builtin_amdgcn_sched_barrier(0);
    __builtin_amdgcn_s_barrier();
    __builtin_amdgcn_sched_barrier(0);
}

// ---------------- fused fp32 -> bf16 cast of all three inputs ----------------
__global__ void cvt_all(const float* __restrict__ x, const float* __restrict__ qw,
                        const float* __restrict__ ow, short* __restrict__ dst) {
    const int X_N  = BB * SS * DD;          // 8388608
    const int QW_N = 3 * DD * DD;           // 3145728
    int i = (blockIdx.x * 256 + threadIdx.x) * 8;
    const float* s;
    if (i < X_N)            s = x + i;
    else if (i < X_N + QW_N) s = qw + (i - X_N);
    else                     s = ow + (i - X_N - QW_N);
    const float4* sp = (const float4*)s;
    float4 a = sp[0], b = sp[1];
    s16x8 o;
    o[0]=f2bf(a.x); o[1]=f2bf(a.y); o[2]=f2bf(a.z); o[3]=f2bf(a.w);
    o[4]=f2bf(b.x); o[5]=f2bf(b.y); o[6]=f2bf(b.z); o[7]=f2bf(b.w);
    *(s16x8*)(dst + i) = o;
}

// ---------------- GEMM C = A @ B^T + bias (BM=BN=128, BK=32, TRIPLE buffer) --------
// r13 structure with the bank-conflict fix: r13's XOR key (row&3) left the 4 lanes
// l15={0,4,8,12} with IDENTICAL granule AND even row -> 4-way conflict (6.29M
// cycles measured). New key (row>>1)&3 makes collisions only {l15, l15+8} pairs =
// 2-way = free (m136). Both sides changed consistently (rule #21): writer source
// granule (lane&3)^((grow>>1)&3); reader granule quad^((l15>>1)&3). Row-base terms
// (mf*16, wm*64, c*16) contribute 0 to the key on both sides - verified.
template<int EPI>
__global__ __launch_bounds__(256, 3)
void gemm128tb(const short* __restrict__ A, const short* __restrict__ Bw,
               const float* __restrict__ bias, float* __restrict__ Cf,
               short* __restrict__ Qo, short* __restrict__ Ko, short* __restrict__ Vo,
               int M, int N, int K, int nbx)
{
    __shared__ short lsA[3][128 * 32];
    __shared__ short lsB[3][128 * 32];

    const int tid  = threadIdx.x;
    const int w    = tid >> 6, lane = tid & 63;
    const int quad = lane >> 4, l15 = lane & 15;
    const int wm = w >> 1, wn = w & 1;
    const int cpx = gridDim.x >> 3;             // T1 XCD swizzle (grid % 8 == 0)
    const int swz = (blockIdx.x & 7) * cpx + (blockIdx.x >> 3);
    const int m0 = (swz / nbx) * 128, n0 = (swz % nbx) * 128;
    const int grow = lane >> 2;                 // row-within-chunk this lane covers
    const int gcol = ((lane & 3) ^ ((grow >> 1) & 3)) * 8;  // inverse-swizzled src granule
    const int rsw = ((l15 >> 1) & 3);           // reader XOR term ((row>>1)&3)

    f32x4 acc[4][4] = {};

    auto issue = [&](int kt, int buf) {
#pragma unroll
        for (int jj = 0; jj < 2; ++jj) {        // A: 128 rows = 8 chunks, 2/wave
            int c = w * 2 + jj;
            GLL(A + (size_t)(m0 + c * 16 + grow) * K + kt * 32 + gcol,
                &lsA[buf][c * 512]);
        }
#pragma unroll
        for (int jj = 0; jj < 2; ++jj) {        // B: 128 rows = 8 chunks, 2/wave
            int c = w * 2 + jj;
            GLL(Bw + (size_t)(n0 + c * 16 + grow) * K + kt * 32 + gcol,
                &lsB[buf][c * 512]);
        }
    };

    const int NT = K >> 5;                      // BK=32 K-tiles (32 here)
    issue(0, 0);
    issue(1, 1);
    int buf = 0;                                // t % 3
    for (int t = 0; t < NT; ++t) {
        lds_barrier();                          // A: buf[(t+2)%3] readers (t-1) done
        const int nb2 = (buf + 2 >= 3) ? buf - 1 : buf + 2;   // (t+2)%3
        if (t + 2 < NT) {
            issue(t + 2, nb2);
            asm volatile("s_waitcnt vmcnt(8)" ::: "memory");   // stage(t) landed; ~free
        } else if (t + 1 < NT) {
            asm volatile("s_waitcnt vmcnt(4)" ::: "memory");
        } else {
            asm volatile("s_waitcnt vmcnt(0)" ::: "memory");
        }
        __builtin_amdgcn_sched_barrier(0);
        __builtin_amdgcn_s_barrier();           // B: tile t fully staged (all waves)
        __builtin_amdgcn_sched_barrier(0);

        s16x8 af[4], bfr[4];
#pragma unroll
        for (int mf = 0; mf < 4; ++mf)
            af[mf] = *(const s16x8*)&lsA[buf][(wm * 64 + mf * 16 + l15) * 32 +
                                             ((quad ^ rsw) * 8)];
#pragma unroll
        for (int nf = 0; nf < 4; ++nf)
            bfr[nf] = *(const s16x8*)&lsB[buf][(wn * 64 + nf * 16 + l15) * 32 +
                                              ((quad ^ rsw) * 8)];

        __builtin_amdgcn_s_setprio(1);
#pragma unroll
        for (int mf = 0; mf < 4; ++mf)
#pragma unroll
            for (int nf = 0; nf < 4; ++nf)
                acc[mf][nf] = __builtin_amdgcn_mfma_f32_16x16x32_bf16(
                                  af[mf], bfr[nf], acc[mf][nf], 0, 0, 0);
        __builtin_amdgcn_s_setprio(0);

        buf = (buf + 1 >= 3) ? 0 : buf + 1;
    }

    if (EPI == 0) {
#pragma unroll
        for (int mf = 0; mf < 4; ++mf) {
            int row = m0 + wm * 64 + mf * 16 + quad * 4;
#pragma unroll
            for (int nf = 0; nf < 4; ++nf) {
                int col = n0 + wn * 64 + nf * 16 + l15;
                float bv = bias[col];
#pragma unroll
                for (int r = 0; r < 4; ++r)
                    Cf[(size_t)(row + r) * N + col] = acc[mf][nf][r] + bv;
            }
        }
    } else {
#pragma unroll
        for (int mf = 0; mf < 4; ++mf) {
            int row = m0 + wm * 64 + mf * 16 + quad * 4;
#pragma unroll
            for (int nf = 0; nf < 4; ++nf) {
                int col = n0 + wn * 64 + nf * 16 + l15;
                float bv = bias[col];
                int sel = col >> 10, h = (col >> 6) & 15, hd = col & 63;
#pragma unroll
                for (int r = 0; r < 4; ++r) {
                    int rr = row + r;
                    int b = rr >> 11, s = rr & 2047;
                    short val = f2bf(acc[mf][nf][r] + bv);
                    if (sel == 0)      Qo[(((size_t)b * HH + h) * SS + s) * HDD + hd] = val;
                    else if (sel == 1) Ko[(((size_t)b * HH + h) * SS + s) * HDD + hd] = val;
                    else               Vo[(((size_t)b * HH + h) * HDD + hd) * SS + s] = val;
                }
            }
        }
    }
}

// ---------------- causal flash attention (swapped QK^T + XCD-affinity remap) -------
// REVERTED to the round-13 version (KVBLK=64; r14's KVBLK=128 was neutral-negative).
__global__ __launch_bounds__(256, 2)
void attn_kernel(const short* __restrict__ Q, const short* __restrict__ Kb,
                 const short* __restrict__ Vb, const int* __restrict__ mask,
                 short* __restrict__ O)
{
    __shared__ short lsK[2][64 * 64];      // [buf][key][hd] linear (GLL), src-swizzled
    __shared__ short lsV[2][64 * 64];      // [buf][hd][key] linear (GLL), src-swizzled
    __shared__ short lsP[4][32 * 64];      // per-wave P [qrow 32][key 64], granule-XOR
    __shared__ short lsM[SS];              // mask additive, bf16 (0 or -1e30)

    const int tid  = threadIdx.x;
    const int w    = tid >> 6, lane = tid & 63;
    const int quad = lane >> 4, l15 = lane & 15;
    const int L  = blockIdx.x + 8 * blockIdx.y;      // [0,512)
    const int bx = L >> 6;                           // [0,8)
    const int bh = (L & 7) * 8 + ((L >> 3) & 7);     // [0,64), same-XCD groups
    const int b = bh >> 4;
    const size_t baseQK = (size_t)bh * SS * HDD;
    const size_t baseV  = (size_t)bh * HDD * SS;
    const float SC = 0.18033688f;          // (1/8) * log2(e)
    const int grow = lane >> 3;            // GLL: row-within-8 covered by this lane
    const int gcol = ((lane & 7) ^ grow) * 8;  // GLL: inverse-swizzled source col (shorts)
    const int l7 = l15 & 7;

    // stage mask -> lsM once (visible after first lds_barrier)
    {
        const int4* mp = (const int4*)(mask + b * SS);
        int4 a = mp[tid * 2], c = mp[tid * 2 + 1];
        const short NEG = f2bf(-1e30f);
        s16x8 mo;
        mo[0] = a.x ? (short)0 : NEG; mo[1] = a.y ? (short)0 : NEG;
        mo[2] = a.z ? (short)0 : NEG; mo[3] = a.w ? (short)0 : NEG;
        mo[4] = c.x ? (short)0 : NEG; mo[5] = c.y ? (short)0 : NEG;
        mo[6] = c.z ? (short)0 : NEG; mo[7] = c.w ? (short)0 : NEG;
        *(s16x8*)&lsM[tid * 8] = mo;
    }

    // issue tile (kv0) K/V global->LDS DMA into buffer buf: 4 GLL per wave
    auto issue = [&](int kv0, int buf) {
#pragma unroll
        for (int jj = 0; jj < 2; ++jj) {
            int row = w * 16 + jj * 8 + grow;                  // key row
            GLL(Kb + baseQK + (size_t)(kv0 + row) * HDD + gcol,
                &lsK[buf][(w * 2 + jj) * 512]);
        }
#pragma unroll
        for (int jj = 0; jj < 2; ++jj) {
            int row = w * 16 + jj * 8 + grow;                  // hd row
            GLL(Vb + baseV + (size_t)row * SS + kv0 + gcol,
                &lsV[buf][(w * 2 + jj) * 512]);
        }
    };

    for (int t = 0; t < 2; ++t) {
        const int qb = t ? bx : (15 - bx);  // heavy q-tile first
        const int q0 = qb * 128;
        const int qw0 = q0 + w * 32;        // this wave's first q-row

        s16x8 aq[2][2];
#pragma unroll
        for (int s = 0; s < 2; ++s)
#pragma unroll
            for (int ks = 0; ks < 2; ++ks)
                aq[s][ks] = *(const s16x8*)(Q + baseQK +
                    (size_t)(qw0 + s * 16 + l15) * HDD + ks * 32 + quad * 8);

        float m_r[2], l_r[2];
        f32x4 o_acc[2][4] = {};
#pragma unroll
        for (int s = 0; s < 2; ++s) { m_r[s] = -1e30f; l_r[s] = 0.f; }

        const int ntiles = 2 * qb + 2;      // 64-key tiles; last two are diagonal

        lds_barrier();                      // prev t's reads done / mask visible
        issue(0, 0);

        auto tile = [&](auto CC, int kv0, int buf, int kvn) {
            constexpr bool CAUS = decltype(CC)::value;

            lds_barrier();                  // A: all waves done reading buf^1
            if (kvn >= 0) issue(kvn, buf ^ 1);

            // mask additive: 4 consecutive k per nt (8B broadcast-friendly read)
            float madd[4][4];
#pragma unroll
            for (int nt = 0; nt < 4; ++nt) {
                uint2 mw4 = *(const uint2*)&lsM[kv0 + nt * 16 + quad * 4];
                madd[nt][0] = bf2f((short)(mw4.x & 0xffff));
                madd[nt][1] = bf2f((short)(mw4.x >> 16));
                madd[nt][2] = bf2f((short)(mw4.y & 0xffff));
                madd[nt][3] = bf2f((short)(mw4.y >> 16));
            }

            if (kvn >= 0) asm volatile("s_waitcnt vmcnt(4)" ::: "memory");
            else          asm volatile("s_waitcnt vmcnt(0)" ::: "memory");
            __builtin_amdgcn_sched_barrier(0);
            __builtin_amdgcn_s_barrier();   // B: all waves' GLLs for buf landed
            __builtin_amdgcn_sched_barrier(0);

            // S^T = K Q^T : D[key][q]; lane holds q=l15, key=kv0+nt*16+quad*4+r
            f32x4 sv[2][4];
#pragma unroll
            for (int s = 0; s < 2; ++s)
#pragma unroll
                for (int nt = 0; nt < 4; ++nt) sv[s][nt] = f32x4{};
#pragma unroll
            for (int ks = 0; ks < 2; ++ks)
#pragma unroll
                for (int nt = 0; nt < 4; ++nt) {
                    s16x8 kf = *(const s16x8*)&lsK[buf][(nt * 16 + l15) * 64 +
                                                       (((ks * 4 + quad) ^ l7) * 8)];
#pragma unroll
                    for (int s = 0; s < 2; ++s)
                        sv[s][nt] = __builtin_amdgcn_mfma_f32_16x16x32_bf16(
                                        kf, aq[s][ks], sv[s][nt], 0, 0, 0);
                }

            // scale + key-mask + causal (k lane-indexed, q = l15)
#pragma unroll
            for (int s = 0; s < 2; ++s) {
                const int qg = qw0 + s * 16 + l15;
#pragma unroll
                for (int nt = 0; nt < 4; ++nt) {
                    const int kg0 = kv0 + nt * 16 + quad * 4;
#pragma unroll
                    for (int r = 0; r < 4; ++r) {
                        float scv = sv[s][nt][r] * SC + madd[nt][r];
                        if (CAUS && kg0 + r > qg) scv = -1e30f;
                        sv[s][nt][r] = scv;
                    }
                }
            }

            // row max over keys: 16 in-lane + cross-quad (2 shfl)
            float rm[2];
#pragma unroll
            for (int s = 0; s < 2; ++s) {
                float v = fmaxf(fmaxf(fmaxf(sv[s][0][0], sv[s][0][1]),
                                      fmaxf(sv[s][0][2], sv[s][0][3])),
                                fmaxf(fmaxf(sv[s][1][0], sv[s][1][1]),
                                      fmaxf(sv[s][1][2], sv[s][1][3])));
                float v2 = fmaxf(fmaxf(fmaxf(sv[s][2][0], sv[s][2][1]),
                                       fmaxf(sv[s][2][2], sv[s][2][3])),
                                 fmaxf(fmaxf(sv[s][3][0], sv[s][3][1]),
                                       fmaxf(sv[s][3][2], sv[s][3][3])));
                v = fmaxf(v, v2);
                v = fmaxf(v, __shfl_xor(v, 16));
                v = fmaxf(v, __shfl_xor(v, 32));
                rm[s] = v;
            }
            // T13 defer-max: rescale only when some row's max grew > 8 (log2 domain)
            float need = fmaxf(rm[0] - m_r[0], rm[1] - m_r[1]);
            if (!__all(need <= 8.0f)) {
#pragma unroll
                for (int s = 0; s < 2; ++s) {
                    float nm = fmaxf(m_r[s], rm[s]);
                    float al = __builtin_amdgcn_exp2f(m_r[s] - nm);
                    m_r[s] = nm;
                    l_r[s] *= al;
#pragma unroll
                    for (int r = 0; r < 4; ++r) {
                        float alq = __shfl(al, (quad << 2) + r + (lane & 48));
#pragma unroll
                        for (int ht = 0; ht < 4; ++ht)
                            o_acc[s][ht][r] *= alq;
                    }
                }
            }
            // P = exp2(S - m); per-lane partial l (cross-quad sum at epilogue)
#pragma unroll
            for (int s = 0; s < 2; ++s) {
                float rs = 0.f;
#pragma unroll
                for (int nt = 0; nt < 4; ++nt)
#pragma unroll
                    for (int r = 0; r < 4; ++r) {
                        float p = __builtin_amdgcn_exp2f(sv[s][nt][r] - m_r[s]);
                        sv[s][nt][r] = p;
                        rs += p;
                    }
                l_r[s] += rs;
            }

            // P -> wave-private buffer: 4 consecutive k per lane = 1 ds_write_b64
            short* lsPw = lsP[w];
#pragma unroll
            for (int s = 0; s < 2; ++s)
#pragma unroll
                for (int nt = 0; nt < 4; ++nt) {
                    uint2 pw;
                    pw.x = pk2(sv[s][nt][0], sv[s][nt][1]);
                    pw.y = pk2(sv[s][nt][2], sv[s][nt][3]);
                    int row = s * 16 + l15;
                    int g8 = (nt * 2 + (quad >> 1)) ^ l7;
                    *(uint2*)&lsPw[row * 64 + (g8 << 3) + ((quad & 1) << 2)] = pw;
                }
            asm volatile("s_waitcnt lgkmcnt(0)" ::: "memory");
            __builtin_amdgcn_sched_barrier(0);

            // O += P V
            s16x8 ap[2][2];
#pragma unroll
            for (int s = 0; s < 2; ++s)
#pragma unroll
                for (int k2 = 0; k2 < 2; ++k2)
                    ap[s][k2] = *(const s16x8*)&lsPw[(s * 16 + l15) * 64 +
                                                     (((k2 * 4 + quad) ^ l7) << 3)];
#pragma unroll
            for (int ht = 0; ht < 4; ++ht)
#pragma unroll
                for (int k2 = 0; k2 < 2; ++k2) {
                    s16x8 vf = *(const s16x8*)&lsV[buf][(ht * 16 + l15) * 64 +
                                                        (((k2 * 4 + quad) ^ l7) * 8)];
#pragma unroll
                    for (int s = 0; s < 2; ++s)
                        o_acc[s][ht] = __builtin_amdgcn_mfma_f32_16x16x32_bf16(
                                           ap[s][k2], vf, o_acc[s][ht], 0, 0, 0);
                }
        };

        for (int kt = 0; kt < ntiles; ++kt) {
            const int kvn = (kt + 1 < ntiles) ? (kt + 1) * 64 : -1;
            if (kt >= 2 * qb) tile(std::true_type{},  kt * 64, kt & 1, kvn);
            else              tile(std::false_type{}, kt * 64, kt & 1, kvn);
        }

        // epilogue: sum l across quads, redistribute to o_acc rows, write O
        const int hcol = (bh & 15) * HDD;
#pragma unroll
        for (int s = 0; s < 2; ++s) {
            float ls = l_r[s];
            ls += __shfl_xor(ls, 16);
            ls += __shfl_xor(ls, 32);      // full row-sum for q = l15
#pragma unroll
            for (int r = 0; r < 4; ++r) {
                float lq = __shfl(ls, (quad << 2) + r + (lane & 48));
                float inv = 1.0f / lq;
                int srow = qw0 + s * 16 + quad * 4 + r;
                size_t base = ((size_t)b * SS + srow) * DD + hcol;
#pragma unroll
                for (int ht = 0; ht < 4; ++ht)
                    O[base + ht * 16 + l15] = f2bf(o_acc[s][ht][r] * inv);
            }
        }
    }
}

// ---------------- launch ----------------
extern "C" void kernel_launch(void* const* d_in, const int* in_sizes, int n_in,
                              void* d_out, int out_size, void* d_ws, size_t ws_size,
                              hipStream_t stream) {
    const float* x     = (const float*)d_in[0];
    const int*   mask  = (const int*)d_in[1];
    const float* qkv_w = (const float*)d_in[2];
    const float* qkv_b = (const float*)d_in[3];
    const float* out_w = (const float*)d_in[4];
    const float* out_b = (const float*)d_in[5];
    float* out = (float*)d_out;

    const size_t M1 = (size_t)BB * SS;       // 8192
    short* ws  = (short*)d_ws;
    short* xb  = ws;
    short* qwb = xb  + M1 * DD;
    short* owb = qwb + (size_t)3 * DD * DD;
    short* Qb  = owb + (size_t)DD * DD;
    short* Kb  = Qb  + M1 * DD;
    short* Vb  = Kb  + M1 * DD;
    short* Ob  = Vb  + M1 * DD;

    // fused cast: (8192*1024 + 3*1024*1024 + 1024*1024) / 8 / 256 = 6144 blocks
    cvt_all<<<6144, 256, 0, stream>>>(x, qkv_w, out_w, ws);

    // qkv: M=8192, N=3072 -> 64 x 24 = 1536 blocks (3/CU by LDS)
    gemm128tb<1><<<1536, 256, 0, stream>>>(xb, qwb, qkv_b, nullptr,
                                           Qb, Kb, Vb, 8192, 3072, 1024, 24);
    attn_kernel<<<dim3(8, BB * HH), 256, 0, stream>>>(Qb, Kb, Vb, mask, Ob);
    // out: M=8192, N=1024 -> 64 x 8 = 512 blocks
    gemm128tb<0><<<512, 256, 0, stream>>>(Ob, owb, out_b, out,
                                          nullptr, nullptr, nullptr, 8192, 1024, 1024, 8);
}

// Round 16
// 282.698 us; speedup vs baseline: 1.0180x; 1.0002x over previous
//
#include <hip/hip_runtime.h>
#include <stdint.h>
#include <type_traits>

// Problem constants
#define BB  4
#define SS  2048
#define DD  1024
#define HH  16
#define HDD 64

typedef __attribute__((ext_vector_type(8))) short s16x8;   // 8 bf16 (4 VGPRs)
typedef __attribute__((ext_vector_type(4))) float f32x4;   // MFMA C/D

__device__ inline short f2bf(float f) {
    union { float f; unsigned int u; } v; v.f = f;
    unsigned int r = (v.u + 0x7fffu + ((v.u >> 16) & 1u)) >> 16; // RNE
    return (short)r;
}

__device__ inline float bf2f(short s) {
    union { unsigned int u; float f; } v;
    v.u = ((unsigned int)(unsigned short)s) << 16;
    return v.f;
}

__device__ inline unsigned int pk2(float a, float b) {
    return (unsigned int)(unsigned short)f2bf(a) |
           ((unsigned int)(unsigned short)f2bf(b) << 16);
}

#define GLL(gp, lp) __builtin_amdgcn_global_load_lds( \
    (const __attribute__((address_space(1))) void*)(gp), \
    (__attribute__((address_space(3))) void*)(lp), 16, 0, 0)

// Raw barrier: orders this wave's LDS ops (lgkmcnt) then syncs. Does NOT
// drain vmcnt -> global_load_lds prefetch stays in flight across it.
__device__ inline void lds_barrier() {
    asm volatile("s_waitcnt lgkmcnt(0)" ::: "memory");
    __builtin_amdgcn_sched_barrier(0);
    __builtin_amdgcn_s_barrier();
    __builtin_amdgcn_sched_barrier(0);
}

// ---------------- fused fp32 -> bf16 cast of all three inputs ----------------
__global__ void cvt_all(const float* __restrict__ x, const float* __restrict__ qw,
                        const float* __restrict__ ow, short* __restrict__ dst) {
    const int X_N  = BB * SS * DD;          // 8388608
    const int QW_N = 3 * DD * DD;           // 3145728
    int i = (blockIdx.x * 256 + threadIdx.x) * 8;
    const float* s;
    if (i < X_N)            s = x + i;
    else if (i < X_N + QW_N) s = qw + (i - X_N);
    else                     s = ow + (i - X_N - QW_N);
    const float4* sp = (const float4*)s;
    float4 a = sp[0], b = sp[1];
    s16x8 o;
    o[0]=f2bf(a.x); o[1]=f2bf(a.y); o[2]=f2bf(a.z); o[3]=f2bf(a.w);
    o[4]=f2bf(b.x); o[5]=f2bf(b.y); o[6]=f2bf(b.z); o[7]=f2bf(b.w);
    *(s16x8*)(dst + i) = o;
}

// ---------------- GEMM C = A @ B^T + bias (BM=BN=128, BK=32, triple buf, 1 barrier)
// r15 structure with barrier A DELETED. Safety argument: a wave arrives at
// barrier B(t) only after issuing all compute(t-1) MFMAs, whose operands force
// compiler lgkmcnt waits -> every wave's tile-(t-1) ds_reads are COMPLETE before
// B(t). So issuing stage(t+2) (which overwrites buf[(t+2)%3] = buf[(t-1)%3],
// last read at compute(t-1)) AFTER B(t) is race-free, and the old barrier A is
// redundant. One barrier per K-tile (32 convoy points deleted).
// vmcnt audit: at top of iter t the FIFO = stage(t)(maybe live) + stage(t+1)(8);
// vmcnt(8) proves stage(t) landed, stage(t+1) stays in flight. vmcnt(0) at last.
// Conflict-free reader/writer XOR key (row>>1)&3 (r15: 6.29M -> 0 measured).
template<int EPI>
__global__ __launch_bounds__(256, 3)
void gemm128tb(const short* __restrict__ A, const short* __restrict__ Bw,
               const float* __restrict__ bias, float* __restrict__ Cf,
               short* __restrict__ Qo, short* __restrict__ Ko, short* __restrict__ Vo,
               int M, int N, int K, int nbx)
{
    __shared__ short lsA[3][128 * 32];
    __shared__ short lsB[3][128 * 32];

    const int tid  = threadIdx.x;
    const int w    = tid >> 6, lane = tid & 63;
    const int quad = lane >> 4, l15 = lane & 15;
    const int wm = w >> 1, wn = w & 1;
    const int cpx = gridDim.x >> 3;             // T1 XCD swizzle (grid % 8 == 0)
    const int swz = (blockIdx.x & 7) * cpx + (blockIdx.x >> 3);
    const int m0 = (swz / nbx) * 128, n0 = (swz % nbx) * 128;
    const int grow = lane >> 2;                 // row-within-chunk this lane covers
    const int gcol = ((lane & 3) ^ ((grow >> 1) & 3)) * 8;  // inverse-swizzled src granule
    const int rsw = ((l15 >> 1) & 3);           // reader XOR term ((row>>1)&3)

    f32x4 acc[4][4] = {};

    auto issue = [&](int kt, int buf) {
#pragma unroll
        for (int jj = 0; jj < 2; ++jj) {        // A: 128 rows = 8 chunks, 2/wave
            int c = w * 2 + jj;
            GLL(A + (size_t)(m0 + c * 16 + grow) * K + kt * 32 + gcol,
                &lsA[buf][c * 512]);
        }
#pragma unroll
        for (int jj = 0; jj < 2; ++jj) {        // B: 128 rows = 8 chunks, 2/wave
            int c = w * 2 + jj;
            GLL(Bw + (size_t)(n0 + c * 16 + grow) * K + kt * 32 + gcol,
                &lsB[buf][c * 512]);
        }
    };

    const int NT = K >> 5;                      // BK=32 K-tiles (32 here)
    issue(0, 0);
    issue(1, 1);
    int buf = 0;                                // t % 3
    for (int t = 0; t < NT; ++t) {
        if (t + 1 < NT) asm volatile("s_waitcnt vmcnt(8)" ::: "memory");
        else            asm volatile("s_waitcnt vmcnt(0)" ::: "memory");
        __builtin_amdgcn_sched_barrier(0);
        __builtin_amdgcn_s_barrier();           // B: tile t staged; compute(t-1) done
        __builtin_amdgcn_sched_barrier(0);

        const int nb2 = (buf + 2 >= 3) ? buf - 1 : buf + 2;   // (t+2)%3
        if (t + 2 < NT) issue(t + 2, nb2);      // overwrites buf last read at t-1

        s16x8 af[4], bfr[4];
#pragma unroll
        for (int mf = 0; mf < 4; ++mf)
            af[mf] = *(const s16x8*)&lsA[buf][(wm * 64 + mf * 16 + l15) * 32 +
                                             ((quad ^ rsw) * 8)];
#pragma unroll
        for (int nf = 0; nf < 4; ++nf)
            bfr[nf] = *(const s16x8*)&lsB[buf][(wn * 64 + nf * 16 + l15) * 32 +
                                              ((quad ^ rsw) * 8)];

        __builtin_amdgcn_s_setprio(1);
#pragma unroll
        for (int mf = 0; mf < 4; ++mf)
#pragma unroll
            for (int nf = 0; nf < 4; ++nf)
                acc[mf][nf] = __builtin_amdgcn_mfma_f32_16x16x32_bf16(
                                  af[mf], bfr[nf], acc[mf][nf], 0, 0, 0);
        __builtin_amdgcn_s_setprio(0);

        buf = (buf + 1 >= 3) ? 0 : buf + 1;
    }

    if (EPI == 0) {
#pragma unroll
        for (int mf = 0; mf < 4; ++mf) {
            int row = m0 + wm * 64 + mf * 16 + quad * 4;
#pragma unroll
            for (int nf = 0; nf < 4; ++nf) {
                int col = n0 + wn * 64 + nf * 16 + l15;
                float bv = bias[col];
#pragma unroll
                for (int r = 0; r < 4; ++r)
                    Cf[(size_t)(row + r) * N + col] = acc[mf][nf][r] + bv;
            }
        }
    } else {
#pragma unroll
        for (int mf = 0; mf < 4; ++mf) {
            int row = m0 + wm * 64 + mf * 16 + quad * 4;
#pragma unroll
            for (int nf = 0; nf < 4; ++nf) {
                int col = n0 + wn * 64 + nf * 16 + l15;
                float bv = bias[col];
                int sel = col >> 10, h = (col >> 6) & 15, hd = col & 63;
#pragma unroll
                for (int r = 0; r < 4; ++r) {
                    int rr = row + r;
                    int b = rr >> 11, s = rr & 2047;
                    short val = f2bf(acc[mf][nf][r] + bv);
                    if (sel == 0)      Qo[(((size_t)b * HH + h) * SS + s) * HDD + hd] = val;
                    else if (sel == 1) Ko[(((size_t)b * HH + h) * SS + s) * HDD + hd] = val;
                    else               Vo[(((size_t)b * HH + h) * HDD + hd) * SS + s] = val;
                }
            }
        }
    }
}

// ---------------- causal flash attention (swapped QK^T + XCD-affinity remap) -------
// (unchanged from round 13/15 known-good version)
__global__ __launch_bounds__(256, 2)
void attn_kernel(const short* __restrict__ Q, const short* __restrict__ Kb,
                 const short* __restrict__ Vb, const int* __restrict__ mask,
                 short* __restrict__ O)
{
    __shared__ short lsK[2][64 * 64];      // [buf][key][hd] linear (GLL), src-swizzled
    __shared__ short lsV[2][64 * 64];      // [buf][hd][key] linear (GLL), src-swizzled
    __shared__ short lsP[4][32 * 64];      // per-wave P [qrow 32][key 64], granule-XOR
    __shared__ short lsM[SS];              // mask additive, bf16 (0 or -1e30)

    const int tid  = threadIdx.x;
    const int w    = tid >> 6, lane = tid & 63;
    const int quad = lane >> 4, l15 = lane & 15;
    const int L  = blockIdx.x + 8 * blockIdx.y;      // [0,512)
    const int bx = L >> 6;                           // [0,8)
    const int bh = (L & 7) * 8 + ((L >> 3) & 7);     // [0,64), same-XCD groups
    const int b = bh >> 4;
    const size_t baseQK = (size_t)bh * SS * HDD;
    const size_t baseV  = (size_t)bh * HDD * SS;
    const float SC = 0.18033688f;          // (1/8) * log2(e)
    const int grow = lane >> 3;            // GLL: row-within-8 covered by this lane
    const int gcol = ((lane & 7) ^ grow) * 8;  // GLL: inverse-swizzled source col (shorts)
    const int l7 = l15 & 7;

    // stage mask -> lsM once (visible after first lds_barrier)
    {
        const int4* mp = (const int4*)(mask + b * SS);
        int4 a = mp[tid * 2], c = mp[tid * 2 + 1];
        const short NEG = f2bf(-1e30f);
        s16x8 mo;
        mo[0] = a.x ? (short)0 : NEG; mo[1] = a.y ? (short)0 : NEG;
        mo[2] = a.z ? (short)0 : NEG; mo[3] = a.w ? (short)0 : NEG;
        mo[4] = c.x ? (short)0 : NEG; mo[5] = c.y ? (short)0 : NEG;
        mo[6] = c.z ? (short)0 : NEG; mo[7] = c.w ? (short)0 : NEG;
        *(s16x8*)&lsM[tid * 8] = mo;
    }

    // issue tile (kv0) K/V global->LDS DMA into buffer buf: 4 GLL per wave
    auto issue = [&](int kv0, int buf) {
#pragma unroll
        for (int jj = 0; jj < 2; ++jj) {
            int row = w * 16 + jj * 8 + grow;                  // key row
            GLL(Kb + baseQK + (size_t)(kv0 + row) * HDD + gcol,
                &lsK[buf][(w * 2 + jj) * 512]);
        }
#pragma unroll
        for (int jj = 0; jj < 2; ++jj) {
            int row = w * 16 + jj * 8 + grow;                  // hd row
            GLL(Vb + baseV + (size_t)row * SS + kv0 + gcol,
                &lsV[buf][(w * 2 + jj) * 512]);
        }
    };

    for (int t = 0; t < 2; ++t) {
        const int qb = t ? bx : (15 - bx);  // heavy q-tile first
        const int q0 = qb * 128;
        const int qw0 = q0 + w * 32;        // this wave's first q-row

        s16x8 aq[2][2];
#pragma unroll
        for (int s = 0; s < 2; ++s)
#pragma unroll
            for (int ks = 0; ks < 2; ++ks)
                aq[s][ks] = *(const s16x8*)(Q + baseQK +
                    (size_t)(qw0 + s * 16 + l15) * HDD + ks * 32 + quad * 8);

        float m_r[2], l_r[2];
        f32x4 o_acc[2][4] = {};
#pragma unroll
        for (int s = 0; s < 2; ++s) { m_r[s] = -1e30f; l_r[s] = 0.f; }

        const int ntiles = 2 * qb + 2;      // 64-key tiles; last two are diagonal

        lds_barrier();                      // prev t's reads done / mask visible
        issue(0, 0);

        auto tile = [&](auto CC, int kv0, int buf, int kvn) {
            constexpr bool CAUS = decltype(CC)::value;

            lds_barrier();                  // A: all waves done reading buf^1
            if (kvn >= 0) issue(kvn, buf ^ 1);

            // mask additive: 4 consecutive k per nt (8B broadcast-friendly read)
            float madd[4][4];
#pragma unroll
            for (int nt = 0; nt < 4; ++nt) {
                uint2 mw4 = *(const uint2*)&lsM[kv0 + nt * 16 + quad * 4];
                madd[nt][0] = bf2f((short)(mw4.x & 0xffff));
                madd[nt][1] = bf2f((short)(mw4.x >> 16));
                madd[nt][2] = bf2f((short)(mw4.y & 0xffff));
                madd[nt][3] = bf2f((short)(mw4.y >> 16));
            }

            if (kvn >= 0) asm volatile("s_waitcnt vmcnt(4)" ::: "memory");
            else          asm volatile("s_waitcnt vmcnt(0)" ::: "memory");
            __builtin_amdgcn_sched_barrier(0);
            __builtin_amdgcn_s_barrier();   // B: all waves' GLLs for buf landed
            __builtin_amdgcn_sched_barrier(0);

            // S^T = K Q^T : D[key][q]; lane holds q=l15, key=kv0+nt*16+quad*4+r
            f32x4 sv[2][4];
#pragma unroll
            for (int s = 0; s < 2; ++s)
#pragma unroll
                for (int nt = 0; nt < 4; ++nt) sv[s][nt] = f32x4{};
#pragma unroll
            for (int ks = 0; ks < 2; ++ks)
#pragma unroll
                for (int nt = 0; nt < 4; ++nt) {
                    s16x8 kf = *(const s16x8*)&lsK[buf][(nt * 16 + l15) * 64 +
                                                       (((ks * 4 + quad) ^ l7) * 8)];
#pragma unroll
                    for (int s = 0; s < 2; ++s)
                        sv[s][nt] = __builtin_amdgcn_mfma_f32_16x16x32_bf16(
                                        kf, aq[s][ks], sv[s][nt], 0, 0, 0);
                }

            // scale + key-mask + causal (k lane-indexed, q = l15)
#pragma unroll
            for (int s = 0; s < 2; ++s) {
                const int qg = qw0 + s * 16 + l15;
#pragma unroll
                for (int nt = 0; nt < 4; ++nt) {
                    const int kg0 = kv0 + nt * 16 + quad * 4;
#pragma unroll
                    for (int r = 0; r < 4; ++r) {
                        float scv = sv[s][nt][r] * SC + madd[nt][r];
                        if (CAUS && kg0 + r > qg) scv = -1e30f;
                        sv[s][nt][r] = scv;
                    }
                }
            }

            // row max over keys: 16 in-lane + cross-quad (2 shfl)
            float rm[2];
#pragma unroll
            for (int s = 0; s < 2; ++s) {
                float v = fmaxf(fmaxf(fmaxf(sv[s][0][0], sv[s][0][1]),
                                      fmaxf(sv[s][0][2], sv[s][0][3])),
                                fmaxf(fmaxf(sv[s][1][0], sv[s][1][1]),
                                      fmaxf(sv[s][1][2], sv[s][1][3])));
                float v2 = fmaxf(fmaxf(fmaxf(sv[s][2][0], sv[s][2][1]),
                                       fmaxf(sv[s][2][2], sv[s][2][3])),
                                 fmaxf(fmaxf(sv[s][3][0], sv[s][3][1]),
                                       fmaxf(sv[s][3][2], sv[s][3][3])));
                v = fmaxf(v, v2);
                v = fmaxf(v, __shfl_xor(v, 16));
                v = fmaxf(v, __shfl_xor(v, 32));
                rm[s] = v;
            }
            // T13 defer-max: rescale only when some row's max grew > 8 (log2 domain)
            float need = fmaxf(rm[0] - m_r[0], rm[1] - m_r[1]);
            if (!__all(need <= 8.0f)) {
#pragma unroll
                for (int s = 0; s < 2; ++s) {
                    float nm = fmaxf(m_r[s], rm[s]);
                    float al = __builtin_amdgcn_exp2f(m_r[s] - nm);
                    m_r[s] = nm;
                    l_r[s] *= al;
#pragma unroll
                    for (int r = 0; r < 4; ++r) {
                        float alq = __shfl(al, (quad << 2) + r + (lane & 48));
#pragma unroll
                        for (int ht = 0; ht < 4; ++ht)
                            o_acc[s][ht][r] *= alq;
                    }
                }
            }
            // P = exp2(S - m); per-lane partial l (cross-quad sum at epilogue)
#pragma unroll
            for (int s = 0; s < 2; ++s) {
                float rs = 0.f;
#pragma unroll
                for (int nt = 0; nt < 4; ++nt)
#pragma unroll
                    for (int r = 0; r < 4; ++r) {
                        float p = __builtin_amdgcn_exp2f(sv[s][nt][r] - m_r[s]);
                        sv[s][nt][r] = p;
                        rs += p;
                    }
                l_r[s] += rs;
            }

            // P -> wave-private buffer: 4 consecutive k per lane = 1 ds_write_b64
            short* lsPw = lsP[w];
#pragma unroll
            for (int s = 0; s < 2; ++s)
#pragma unroll
                for (int nt = 0; nt < 4; ++nt) {
                    uint2 pw;
                    pw.x = pk2(sv[s][nt][0], sv[s][nt][1]);
                    pw.y = pk2(sv[s][nt][2], sv[s][nt][3]);
                    int row = s * 16 + l15;
                    int g8 = (nt * 2 + (quad >> 1)) ^ l7;
                    *(uint2*)&lsPw[row * 64 + (g8 << 3) + ((quad & 1) << 2)] = pw;
                }
            asm volatile("s_waitcnt lgkmcnt(0)" ::: "memory");
            __builtin_amdgcn_sched_barrier(0);

            // O += P V
            s16x8 ap[2][2];
#pragma unroll
            for (int s = 0; s < 2; ++s)
#pragma unroll
                for (int k2 = 0; k2 < 2; ++k2)
                    ap[s][k2] = *(const s16x8*)&lsPw[(s * 16 + l15) * 64 +
                                                     (((k2 * 4 + quad) ^ l7) << 3)];
#pragma unroll
            for (int ht = 0; ht < 4; ++ht)
#pragma unroll
                for (int k2 = 0; k2 < 2; ++k2) {
                    s16x8 vf = *(const s16x8*)&lsV[buf][(ht * 16 + l15) * 64 +
                                                        (((k2 * 4 + quad) ^ l7) * 8)];
#pragma unroll
                    for (int s = 0; s < 2; ++s)
                        o_acc[s][ht] = __builtin_amdgcn_mfma_f32_16x16x32_bf16(
                                           ap[s][k2], vf, o_acc[s][ht], 0, 0, 0);
                }
        };

        for (int kt = 0; kt < ntiles; ++kt) {
            const int kvn = (kt + 1 < ntiles) ? (kt + 1) * 64 : -1;
            if (kt >= 2 * qb) tile(std::true_type{},  kt * 64, kt & 1, kvn);
            else              tile(std::false_type{}, kt * 64, kt & 1, kvn);
        }

        // epilogue: sum l across quads, redistribute to o_acc rows, write O
        const int hcol = (bh & 15) * HDD;
#pragma unroll
        for (int s = 0; s < 2; ++s) {
            float ls = l_r[s];
            ls += __shfl_xor(ls, 16);
            ls += __shfl_xor(ls, 32);      // full row-sum for q = l15
#pragma unroll
            for (int r = 0; r < 4; ++r) {
                float lq = __shfl(ls, (quad << 2) + r + (lane & 48));
                float inv = 1.0f / lq;
                int srow = qw0 + s * 16 + quad * 4 + r;
                size_t base = ((size_t)b * SS + srow) * DD + hcol;
#pragma unroll
                for (int ht = 0; ht < 4; ++ht)
                    O[base + ht * 16 + l15] = f2bf(o_acc[s][ht][r] * inv);
            }
        }
    }
}

// ---------------- launch ----------------
extern "C" void kernel_launch(void* const* d_in, const int* in_sizes, int n_in,
                              void* d_out, int out_size, void* d_ws, size_t ws_size,
                              hipStream_t stream) {
    const float* x     = (const float*)d_in[0];
    const int*   mask  = (const int*)d_in[1];
    const float* qkv_w = (const float*)d_in[2];
    const float* qkv_b = (const float*)d_in[3];
    const float* out_w = (const float*)d_in[4];
    const float* out_b = (const float*)d_in[5];
    float* out = (float*)d_out;

    const size_t M1 = (size_t)BB * SS;       // 8192
    short* ws  = (short*)d_ws;
    short* xb  = ws;
    short* qwb = xb  + M1 * DD;
    short* owb = qwb + (size_t)3 * DD * DD;
    short* Qb  = owb + (size_t)DD * DD;
    short* Kb  = Qb  + M1 * DD;
    short* Vb  = Kb  + M1 * DD;
    short* Ob  = Vb  + M1 * DD;

    // fused cast: (8192*1024 + 3*1024*1024 + 1024*1024) / 8 / 256 = 6144 blocks
    cvt_all<<<6144, 256, 0, stream>>>(x, qkv_w, out_w, ws);

    // qkv: M=8192, N=3072 -> 64 x 24 = 1536 blocks (3/CU by LDS)
    gemm128tb<1><<<1536, 256, 0, stream>>>(xb, qwb, qkv_b, nullptr,
                                           Qb, Kb, Vb, 8192, 3072, 1024, 24);
    attn_kernel<<<dim3(8, BB * HH), 256, 0, stream>>>(Qb, Kb, Vb, mask, Ob);
    // out: M=8192, N=1024 -> 64 x 8 = 512 blocks
    gemm128tb<0><<<512, 256, 0, stream>>>(Ob, owb, out_b, out,
                                          nullptr, nullptr, nullptr, 8192, 1024, 1024, 8);
}